// Round 3
// baseline (76.467 us; speedup 1.0000x reference)
//
#include <hip/hip_runtime.h>
#include <math.h>

#define N_EXPERTS 64
#define BLOCK 256

// Kernel 1: per-block expert histogram -> hist[block][64] in d_ws.
// Plain stores overwrite the poisoned workspace, so no memset is needed.
__global__ __launch_bounds__(BLOCK) void ExpertCapacityBuffer_hist_kernel(
    const int* __restrict__ experts,   // (N, 2) int32
    int*       __restrict__ hist,      // (nblocks, 64)
    int N)
{
    __shared__ int local_cnt[N_EXPERTS];
    const int tid = threadIdx.x;
    if (tid < N_EXPERTS) local_cnt[tid] = 0;
    __syncthreads();

    const int t = blockIdx.x * BLOCK + tid;
    if (t < N) {
        const int2 ev = ((const int2*)experts)[t];
        atomicAdd(&local_cnt[ev.x], 1);
        atomicAdd(&local_cnt[ev.y], 1);
    }
    __syncthreads();

    if (tid < N_EXPERTS) hist[blockIdx.x * N_EXPERTS + tid] = local_cnt[tid];
}

// Kernel 2: recompute local ranks (LDS atomics), block base = prefix sum of
// hist over blocks b' < blockIdx (L2-resident, 4 threads per expert), then
// apply the capacity mask and write all three outputs.
__global__ __launch_bounds__(BLOCK) void ExpertCapacityBuffer_main_kernel(
    const float* __restrict__ weights,  // (N, 2) float32
    const int*   __restrict__ experts,  // (N, 2) int32
    float*       __restrict__ out,      // [0,2N) wc, [2N,4N) idx, [4N,5N) overflow
    const int*   __restrict__ hist,     // (nblocks, 64)
    int N, int capacity)
{
    __shared__ int local_cnt[N_EXPERTS];
    __shared__ int base[N_EXPERTS];
    __shared__ int partial[BLOCK];

    const int tid = threadIdx.x;
    if (tid < N_EXPERTS) local_cnt[tid] = 0;
    __syncthreads();

    const int t = blockIdx.x * BLOCK + tid;
    const bool act = (t < N);
    float2 wv = make_float2(0.f, 0.f);
    int2   ev = make_int2(0, 0);
    int r0 = 0, r1 = 0;
    if (act) {
        wv = ((const float2*)weights)[t];
        ev = ((const int2*)experts)[t];
        r0 = atomicAdd(&local_cnt[ev.x], 1);
        r1 = atomicAdd(&local_cnt[ev.y], 1);
    }

    // Prefix over preceding blocks: thread = (expert e, part p), 4 parts/expert.
    const int e = tid & (N_EXPERTS - 1);
    const int part = tid >> 6;
    int s = 0;
    for (int b = part; b < (int)blockIdx.x; b += 4)
        s += hist[b * N_EXPERTS + e];
    partial[tid] = s;
    __syncthreads();

    if (tid < N_EXPERTS)
        base[tid] = partial[tid] + partial[tid + 64] + partial[tid + 128] + partial[tid + 192];
    __syncthreads();

    if (act) {
        const int rank0 = base[ev.x] + r0;
        const int rank1 = base[ev.y] + r1;
        const float wc0 = (rank0 < capacity) ? wv.x : 0.0f;
        const float wc1 = (rank1 < capacity) ? wv.y : 0.0f;

        ((float2*)out)[t] = make_float2(wc0, wc1);                     // weights_capped
        ((float2*)(out + 2 * (size_t)N))[t] =
            make_float2((float)ev.x, (float)ev.y);                     // expert_indices
        out[4 * (size_t)N + t] = ((wc0 + wc1) == 0.0f) ? 1.0f : 0.0f;  // overflow_mask
    }
}

extern "C" void kernel_launch(void* const* d_in, const int* in_sizes, int n_in,
                              void* d_out, int out_size, void* d_ws, size_t ws_size,
                              hipStream_t stream) {
    const float* weights = (const float*)d_in[0];
    const int*   experts = (const int*)d_in[1];
    float*       out     = (float*)d_out;

    const int N = in_sizes[0] / 2;                       // tokens (top_k = 2)
    int capacity = (int)ceil(1.25 * (double)N * 2.0 / (double)N_EXPERTS);
    if (capacity < 1) capacity = 1;

    int* hist = (int*)d_ws;                              // (blocks, 64) ints
    const int blocks = (N + BLOCK - 1) / BLOCK;

    hipLaunchKernelGGL(ExpertCapacityBuffer_hist_kernel,
                       dim3(blocks), dim3(BLOCK), 0, stream,
                       experts, hist, N);
    hipLaunchKernelGGL(ExpertCapacityBuffer_main_kernel,
                       dim3(blocks), dim3(BLOCK), 0, stream,
                       weights, experts, out, hist, N, capacity);
}

// Round 4
// 60.808 us; speedup vs baseline: 1.2575x; 1.2575x over previous
//
#include <hip/hip_runtime.h>
#include <math.h>

#define N_EXPERTS 64
#define BLOCK 256
#define PPT 2                      // token-PAIRS per thread (2 tokens each)
#define PAD 32                     // ints per counter -> each on its own 128-B line

// 128 blocks x 256 threads x 2 pairs x 2 tokens = 131072 tokens.
// Per-block LDS histogram (local ranks in registers), ONE padded global
// atomicAdd per (block, expert): 128 atomics per counter line, 64 parallel
// per-line chains in L2. All global loads/stores are 16 B vectorized.
__global__ __launch_bounds__(BLOCK) void ExpertCapacityBuffer_80444737454353_kernel(
    const float* __restrict__ weights,   // (N, 2) float32
    const int*   __restrict__ experts,   // (N, 2) int32
    float*       __restrict__ out,       // [0,2N) wc, [2N,4N) idx, [4N,5N) overflow
    int*         __restrict__ counts,    // 64 * PAD ints, zeroed
    int N, int capacity)
{
    __shared__ int local_cnt[N_EXPERTS];
    __shared__ int base[N_EXPERTS];

    const int tid = threadIdx.x;
    if (tid < N_EXPERTS) local_cnt[tid] = 0;
    __syncthreads();

    const int P = N >> 1;                       // token pairs
    const int block_p0 = blockIdx.x * (BLOCK * PPT);

    float4 wv[PPT];
    int4   ev[PPT];
    int    r0[PPT], r1[PPT], r2[PPT], r3[PPT];
    bool   act[PPT];

    // Pass 1: vector loads + local ranks via LDS atomics
    #pragma unroll
    for (int i = 0; i < PPT; ++i) {
        const int p = block_p0 + i * BLOCK + tid;
        act[i] = (p < P);
        if (act[i]) {
            wv[i] = ((const float4*)weights)[p];
            ev[i] = ((const int4*)experts)[p];
            r0[i] = atomicAdd(&local_cnt[ev[i].x], 1);
            r1[i] = atomicAdd(&local_cnt[ev[i].y], 1);
            r2[i] = atomicAdd(&local_cnt[ev[i].z], 1);
            r3[i] = atomicAdd(&local_cnt[ev[i].w], 1);
        }
    }
    __syncthreads();

    // One padded global atomic per (block, expert)
    if (tid < N_EXPERTS) {
        int c = local_cnt[tid];
        base[tid] = (c > 0) ? atomicAdd(&counts[tid * PAD], c) : 0;
    }
    __syncthreads();

    // Pass 2: capacity mask + vectorized output writes
    #pragma unroll
    for (int i = 0; i < PPT; ++i) {
        if (act[i]) {
            const int p = block_p0 + i * BLOCK + tid;
            const float wc0 = (base[ev[i].x] + r0[i] < capacity) ? wv[i].x : 0.0f;
            const float wc1 = (base[ev[i].y] + r1[i] < capacity) ? wv[i].y : 0.0f;
            const float wc2 = (base[ev[i].z] + r2[i] < capacity) ? wv[i].z : 0.0f;
            const float wc3 = (base[ev[i].w] + r3[i] < capacity) ? wv[i].w : 0.0f;

            ((float4*)out)[p] = make_float4(wc0, wc1, wc2, wc3);          // weights_capped
            ((float4*)(out + 2 * (size_t)N))[p] =
                make_float4((float)ev[i].x, (float)ev[i].y,
                            (float)ev[i].z, (float)ev[i].w);              // expert_indices
            ((float2*)(out + 4 * (size_t)N))[p] =
                make_float2(((wc0 + wc1) == 0.0f) ? 1.0f : 0.0f,
                            ((wc2 + wc3) == 0.0f) ? 1.0f : 0.0f);         // overflow_mask
        }
    }
}

extern "C" void kernel_launch(void* const* d_in, const int* in_sizes, int n_in,
                              void* d_out, int out_size, void* d_ws, size_t ws_size,
                              hipStream_t stream) {
    const float* weights = (const float*)d_in[0];
    const int*   experts = (const int*)d_in[1];
    float*       out     = (float*)d_out;

    const int N = in_sizes[0] / 2;                       // tokens (top_k = 2)
    int capacity = (int)ceil(1.25 * (double)N * 2.0 / (double)N_EXPERTS);
    if (capacity < 1) capacity = 1;

    int* counts = (int*)d_ws;
    hipMemsetAsync(d_ws, 0, N_EXPERTS * PAD * sizeof(int), stream);

    const int pairs = N >> 1;
    const int pairs_per_block = BLOCK * PPT;
    const int blocks = (pairs + pairs_per_block - 1) / pairs_per_block;
    hipLaunchKernelGGL(ExpertCapacityBuffer_80444737454353_kernel,
                       dim3(blocks), dim3(BLOCK), 0, stream,
                       weights, experts, out, counts, N, capacity);
}